// Round 6
// baseline (256.449 us; speedup 1.0000x reference)
//
#include <hip/hip_runtime.h>
#include <math.h>

#define B 128
#define E 6
#define IN_DIM 1664
#define H_DIM 512
#define OUT_DIM 618
#define ZD 32
#define K2 544
#define KB1 52            // k32-blocks in L1
#define KB23 17           // k32-blocks in L2/L3
#define NPAD3 640         // L3 padded col space (frags + partials)
#define S1 13             // L1 split-K (KPB=4)
#define GRID 256
#define NT 256

typedef __attribute__((ext_vector_type(8))) short short8;
typedef __attribute__((ext_vector_type(4))) float f32x4;
union U128 { uint4 u4; short8 s8; ushort us[8]; };

__device__ __forceinline__ ushort f2bf(float f) {   // fp32 -> bf16 RNE
    uint u = __float_as_uint(f);
    u += 0x7fffu + ((u >> 16) & 1u);
    return (ushort)(u >> 16);
}
__device__ __forceinline__ uint pk2(float a, float b) {
    return (uint)f2bf(a) | ((uint)f2bf(b) << 16);
}

// Device-scope grid barrier (cross-XCD safe): release-fence + atomic arrive,
// thread-0 spin on agent-scope load, acquire-fence after release observed.
// bars[] zeroed per call by captured hipMemsetAsync.
__device__ __forceinline__ void gbar(int* bars, int i) {
    __syncthreads();
    if (threadIdx.x == 0) {
        __threadfence();                       // flush XCD L2 (release)
        atomicAdd(&bars[i], 1);                // device-scope by default
        while (__hip_atomic_load(&bars[i], __ATOMIC_RELAXED,
                                 __HIP_MEMORY_SCOPE_AGENT) < GRID)
            __builtin_amdgcn_s_sleep(1);
    }
    __syncthreads();
    __threadfence();                           // invalidate stale lines (acquire)
}

// ---------------------------------------------------------------------------
// One gemm job: block tile 128 rows x 32 cols at (nt, sp), NS = E*KPB steps.
// Per step (e,kb): W fp32 32k x 32n tile -> regs -> bf16 -> LDS frag layout
// (double-buffered, 1 barrier/step); A-frags preconverted in global. 2-deep
// register prefetch covers L2/L3 latency. Frag math HW-validated (r3-r5).
// ---------------------------------------------------------------------------
template<int KBTOT, int KPB, int NW, int NP>
__device__ __forceinline__ void gemm_job(
    const uint4* __restrict__ afrag,   // [E][KBTOT][8][64] 16B frags
    const float* __restrict__ w,       // [E][KBTOT*32][NW] fp32
    float* __restrict__ part,          // [S][B][NP]
    int nt, int sp, ushort (*bs)[2][64][8])
{
    constexpr int NS = E * KPB;
    const int tid = threadIdx.x;
    const int l  = tid & 63;
    const int wv = tid >> 6;
    const int n0 = nt * 32;
    const int kb0 = sp * KPB;
    const int tn  = tid & 31;
    const int tkq = tid >> 5;                        // 0..7
    const int lp  = ((tkq >> 1) << 4) | (tn & 15);   // frag lane
    const int fI  = tn >> 4;                         // frag 0/1
    const int j0  = (tkq & 1) << 2;                  // j offset 0/4
    const int colW = n0 + tn;

    auto ld_B = [&](int s, float* r) {
        const int e = s % E, kb = kb0 + s / E;
        const float* src = w + ((size_t)e * (KBTOT * 32) + kb * 32 + tkq * 4) * NW + colW;
        #pragma unroll
        for (int j = 0; j < 4; ++j)
            r[j] = (NW == NP || colW < NW) ? src[(size_t)j * NW] : 0.f;
    };
    auto ld_A = [&](int s, U128& x0, U128& x1) {
        const int e = s % E, kb = kb0 + s / E;
        const size_t ab = ((size_t)e * KBTOT + kb) * 8;
        x0.u4 = afrag[(ab + 2 * wv) * 64 + l];
        x1.u4 = afrag[(ab + 2 * wv + 1) * 64 + l];
    };

    f32x4 acc00 = {0.f,0.f,0.f,0.f}, acc01 = {0.f,0.f,0.f,0.f};
    f32x4 acc10 = {0.f,0.f,0.f,0.f}, acc11 = {0.f,0.f,0.f,0.f};

    float wreg[2][4];
    U128  areg[2][2];

    __syncthreads();                     // previous job's LDS reads done
    ld_B(0, wreg[0]); ld_A(0, areg[0][0], areg[0][1]);
    if (NS > 1) { ld_B(1, wreg[1]); ld_A(1, areg[1][0], areg[1][1]); }

    #pragma unroll
    for (int s = 0; s < NS; ++s) {
        const int pb_ = s & 1;
        uint2 pk;
        pk.x = pk2(wreg[pb_][0], wreg[pb_][1]);
        pk.y = pk2(wreg[pb_][2], wreg[pb_][3]);
        *reinterpret_cast<uint2*>(&bs[pb_][fI][lp][j0]) = pk;
        U128 a0 = areg[pb_][0], a1 = areg[pb_][1];
        if (s + 2 < NS) {                // prefetch 2 ahead into freed slot
            ld_B(s + 2, wreg[pb_]);
            ld_A(s + 2, areg[pb_][0], areg[pb_][1]);
        }
        __syncthreads();                 // bs[pb_] visible (1 barrier/step)
        U128 b0, b1;
        b0.u4 = *reinterpret_cast<const uint4*>(&bs[pb_][0][l][0]);
        b1.u4 = *reinterpret_cast<const uint4*>(&bs[pb_][1][l][0]);
        acc00 = __builtin_amdgcn_mfma_f32_16x16x32_bf16(a0.s8, b0.s8, acc00, 0, 0, 0);
        acc01 = __builtin_amdgcn_mfma_f32_16x16x32_bf16(a0.s8, b1.s8, acc01, 0, 0, 0);
        acc10 = __builtin_amdgcn_mfma_f32_16x16x32_bf16(a1.s8, b0.s8, acc10, 0, 0, 0);
        acc11 = __builtin_amdgcn_mfma_f32_16x16x32_bf16(a1.s8, b1.s8, acc11, 0, 0, 0);
    }

    // C/D: col = l&15, row = (l>>4)*4 + r  (HW-validated)
    float* pb = part + (size_t)sp * B * NP;
    const int colB = n0 + (l & 15);
    const int rsub = (l >> 4) << 2;
    #pragma unroll
    for (int mi = 0; mi < 2; ++mi) {
        const int row = wv * 32 + mi * 16 + rsub;
        const f32x4 c0 = mi ? acc10 : acc00;
        const f32x4 c1 = mi ? acc11 : acc01;
        #pragma unroll
        for (int r = 0; r < 4; ++r) {
            pb[(size_t)(row + r) * NP + colB]      = c0[r];
            pb[(size_t)(row + r) * NP + colB + 16] = c1[r];
        }
    }
}

// finalize mid-layer: reduce split-K + blended bias + ELU, emit next A-frags
// (coef-folded bf16, incl. z cols). Thread owns (b, 4 consecutive k).
template<int S>
__device__ __forceinline__ void fin_mid(
    const float* __restrict__ part, const float* __restrict__ coef,
    const float* __restrict__ bias, const float* __restrict__ z,
    ushort* __restrict__ anext)
{
    for (int idx = blockIdx.x * NT + threadIdx.x; idx < B * (K2 / 4);
         idx += GRID * NT) {
        const int b  = idx / (K2 / 4);
        const int o4 = (idx % (K2 / 4)) * 4;

        float vx, vy, vz2, vw;
        if (o4 < H_DIM) {
            float s0 = 0.f, s1 = 0.f, s2 = 0.f, s3 = 0.f;
            #pragma unroll 4
            for (int s = 0; s < S; ++s) {
                const float4 p = *reinterpret_cast<const float4*>(
                    part + ((size_t)s * B + b) * H_DIM + o4);
                s0 += p.x; s1 += p.y; s2 += p.z; s3 += p.w;
            }
            #pragma unroll
            for (int e = 0; e < E; ++e) {
                const float c = coef[b * E + e];
                const float4 bb = *reinterpret_cast<const float4*>(
                    bias + (size_t)e * H_DIM + o4);
                s0 = fmaf(c, bb.x, s0); s1 = fmaf(c, bb.y, s1);
                s2 = fmaf(c, bb.z, s2); s3 = fmaf(c, bb.w, s3);
            }
            vx  = s0 < 0.f ? expm1f(s0) : s0;
            vy  = s1 < 0.f ? expm1f(s1) : s1;
            vz2 = s2 < 0.f ? expm1f(s2) : s2;
            vw  = s3 < 0.f ? expm1f(s3) : s3;
        } else {
            const float4 zv = *reinterpret_cast<const float4*>(
                z + b * ZD + (o4 - H_DIM));
            vx = zv.x; vy = zv.y; vz2 = zv.z; vw = zv.w;
        }

        const int kb = o4 >> 5;
        const int l  = (((o4 >> 3) & 3) << 4) | (b & 15);
        const int j0 = o4 & 7;
        const int m  = b >> 4;
        #pragma unroll
        for (int e = 0; e < E; ++e) {
            const float c = coef[b * E + e];
            uint2 pk;
            pk.x = pk2(vx * c, vy * c);
            pk.y = pk2(vz2 * c, vw * c);
            *reinterpret_cast<uint2*>(
                anext + ((((size_t)e * KB23 + kb) * 8 + m) * 64 + l) * 8 + j0) = pk;
        }
    }
}

// ---------------------------------------------------------------------------
// The whole network in one persistent kernel. 256 blocks x 256 threads
// (co-resident by construction: 4 waves/block fit any CU at any VGPR count).
// ---------------------------------------------------------------------------
__global__ __launch_bounds__(NT) void moe_net(
    const float* __restrict__ x, const float* __restrict__ coef,
    const float* __restrict__ z,
    const float* __restrict__ w1, const float* __restrict__ b1,
    const float* __restrict__ w2, const float* __restrict__ b2,
    const float* __restrict__ w3, const float* __restrict__ b3,
    ushort* a1, ushort* a2, ushort* a3, float* part,
    int* bars, float* out)
{
    __shared__ ushort bs[2][2][64][8];   // dbuf x frag x lane x j, 4 KB
    const int bid = blockIdx.x;
    const int tid = threadIdx.x;

    // P0: A1 frags [E][KB1][8][64][8]
    for (int u = bid * NT + tid; u < E * KB1 * 8 * 64; u += GRID * NT) {
        const int l = u & 63;
        int t = u >> 6;
        const int m = t & 7; t >>= 3;
        const int kb = t % KB1; const int e = t / KB1;
        const int row = m * 16 + (l & 15);
        const int k0  = kb * 32 + ((l >> 4) << 3);
        const float c = coef[row * E + e];
        const float4 v0 = *reinterpret_cast<const float4*>(x + (size_t)row * IN_DIM + k0);
        const float4 v1 = *reinterpret_cast<const float4*>(x + (size_t)row * IN_DIM + k0 + 4);
        U128 r;
        r.us[0] = f2bf(v0.x * c); r.us[1] = f2bf(v0.y * c);
        r.us[2] = f2bf(v0.z * c); r.us[3] = f2bf(v0.w * c);
        r.us[4] = f2bf(v1.x * c); r.us[5] = f2bf(v1.y * c);
        r.us[6] = f2bf(v1.z * c); r.us[7] = f2bf(v1.w * c);
        *reinterpret_cast<uint4*>(a1 + (size_t)u * 8) = r.u4;
    }
    gbar(bars, 0);

    // P1: L1 gemm — 16 n-tiles x 13 splits (KPB=4), <=1 job/block
    for (int job = bid; job < 16 * S1; job += GRID)
        gemm_job<KB1, 4, H_DIM, H_DIM>((const uint4*)a1, w1, part,
                                       job & 15, job >> 4, bs);
    gbar(bars, 1);

    // P2: fin1 -> a2
    fin_mid<S1>(part, coef, b1, z, a2);
    gbar(bars, 2);

    // P3: L2 gemm — 16 x 17
    for (int job = bid; job < 16 * KB23; job += GRID)
        gemm_job<KB23, 1, H_DIM, H_DIM>((const uint4*)a2, w2, part,
                                        job & 15, job >> 4, bs);
    gbar(bars, 3);

    // P4: fin2 -> a3
    fin_mid<KB23>(part, coef, b2, z, a3);
    gbar(bars, 4);

    // P5: L3 gemm — 20 x 17, cols padded to 640
    for (int job = bid; job < 20 * KB23; job += GRID)
        gemm_job<KB23, 1, OUT_DIM, NPAD3>((const uint4*)a3, w3, part,
                                          job % 20, job / 20, bs);
    gbar(bars, 5);

    // P6: fin3 -> out
    for (int idx = bid * NT + tid; idx < B * OUT_DIM; idx += GRID * NT) {
        const int b = idx / OUT_DIM;
        const int o = idx - b * OUT_DIM;
        float v = 0.f;
        #pragma unroll 4
        for (int s = 0; s < KB23; ++s)
            v += part[((size_t)s * B + b) * NPAD3 + o];
        #pragma unroll
        for (int e = 0; e < E; ++e)
            v = fmaf(coef[b * E + e], b3[(size_t)e * OUT_DIM + o], v);
        out[idx] = v;
    }
}

extern "C" void kernel_launch(void* const* d_in, const int* in_sizes, int n_in,
                              void* d_out, int out_size, void* d_ws, size_t ws_size,
                              hipStream_t stream)
{
    const float* p_prev = (const float*)d_in[0];
    const float* coef   = (const float*)d_in[1];
    const float* z      = (const float*)d_in[2];
    const float* w1     = (const float*)d_in[3];
    const float* b1     = (const float*)d_in[4];
    const float* w2     = (const float*)d_in[5];
    const float* b2     = (const float*)d_in[6];
    const float* w3     = (const float*)d_in[7];
    const float* b3     = (const float*)d_in[8];
    float* out = (float*)d_out;

    // ws layout: bars | a1 | a2 | a3 | part   (~9.8 MB total)
    char* p = (char*)d_ws;
    int* bars = (int*)p;     p += 256;
    ushort* a1 = (ushort*)p; p += (size_t)E * KB1  * 8 * 64 * 16;  // 2,555,904
    ushort* a2 = (ushort*)p; p += (size_t)E * KB23 * 8 * 64 * 16;  //   835,584
    ushort* a3 = (ushort*)p; p += (size_t)E * KB23 * 8 * 64 * 16;  //   835,584
    float* part = (float*)p;  // max(13*B*512, 17*B*640)*4 = 5,570,560

    hipMemsetAsync(bars, 0, 256, stream);   // reset grid-barrier slots
    moe_net<<<GRID, NT, 0, stream>>>(p_prev, coef, z, w1, b1, w2, b2, w3, b3,
                                     a1, a2, a3, part, bars, out);
}

// Round 7
// 255.887 us; speedup vs baseline: 1.0022x; 1.0022x over previous
//
#include <hip/hip_runtime.h>
#include <math.h>

#define B 128
#define E 6
#define IN_DIM 1664
#define H_DIM 512
#define OUT_DIM 618
#define ZD 32
#define K2 544
#define KB1 52            // k32-blocks in L1
#define KB23 17           // k32-blocks in L2/L3
#define NPAD3 640         // L3 padded col space (frags + partials)
#define S1 13             // L1 split-K (KPB=4)
#define GRID 256
#define NT 256

typedef __attribute__((ext_vector_type(8))) short short8;
typedef __attribute__((ext_vector_type(4))) float f32x4;
union U128 { uint4 u4; short8 s8; ushort us[8]; };

__device__ __forceinline__ ushort f2bf(float f) {   // fp32 -> bf16 RNE
    uint u = __float_as_uint(f);
    u += 0x7fffu + ((u >> 16) & 1u);
    return (ushort)(u >> 16);
}
__device__ __forceinline__ uint pk2(float a, float b) {
    return (uint)f2bf(a) | ((uint)f2bf(b) << 16);
}

// Device-scope grid barrier (cross-XCD safe): release-fence + atomic arrive,
// thread-0 spin on agent-scope load, acquire-fence after release observed.
// bars[] zeroed per call by captured hipMemsetAsync.
__device__ __forceinline__ void gbar(int* bars, int i) {
    __syncthreads();
    if (threadIdx.x == 0) {
        __threadfence();                       // flush XCD L2 (release)
        atomicAdd(&bars[i], 1);                // device-scope by default
        while (__hip_atomic_load(&bars[i], __ATOMIC_RELAXED,
                                 __HIP_MEMORY_SCOPE_AGENT) < GRID)
            __builtin_amdgcn_s_sleep(1);
    }
    __syncthreads();
    __threadfence();                           // invalidate stale lines (acquire)
}

// ---------------------------------------------------------------------------
// One gemm job: block tile 128 rows x 32 cols at (nt, sp), NS = E*KPB steps.
// Per step (e,kb): W fp32 32k x 32n tile -> regs -> bf16 -> LDS frag layout
// (double-buffered, 1 barrier/step); A-frags preconverted in global. 2-deep
// register prefetch covers L2/L3 latency. Frag math HW-validated (r3-r5).
// ---------------------------------------------------------------------------
template<int KBTOT, int KPB, int NW, int NP>
__device__ __forceinline__ void gemm_job(
    const uint4* __restrict__ afrag,   // [E][KBTOT][8][64] 16B frags
    const float* __restrict__ w,       // [E][KBTOT*32][NW] fp32
    float* __restrict__ part,          // [S][B][NP]
    int nt, int sp, ushort (*bs)[2][64][8])
{
    constexpr int NS = E * KPB;
    const int tid = threadIdx.x;
    const int l  = tid & 63;
    const int wv = tid >> 6;
    const int n0 = nt * 32;
    const int kb0 = sp * KPB;
    const int tn  = tid & 31;
    const int tkq = tid >> 5;                        // 0..7
    const int lp  = ((tkq >> 1) << 4) | (tn & 15);   // frag lane
    const int fI  = tn >> 4;                         // frag 0/1
    const int j0  = (tkq & 1) << 2;                  // j offset 0/4
    const int colW = n0 + tn;

    auto ld_B = [&](int s, float* r) {
        const int e = s % E, kb = kb0 + s / E;
        const float* src = w + ((size_t)e * (KBTOT * 32) + kb * 32 + tkq * 4) * NW + colW;
        #pragma unroll
        for (int j = 0; j < 4; ++j)
            r[j] = (NW == NP || colW < NW) ? src[(size_t)j * NW] : 0.f;
    };
    auto ld_A = [&](int s, U128& x0, U128& x1) {
        const int e = s % E, kb = kb0 + s / E;
        const size_t ab = ((size_t)e * KBTOT + kb) * 8;
        x0.u4 = afrag[(ab + 2 * wv) * 64 + l];
        x1.u4 = afrag[(ab + 2 * wv + 1) * 64 + l];
    };

    f32x4 acc00 = {0.f,0.f,0.f,0.f}, acc01 = {0.f,0.f,0.f,0.f};
    f32x4 acc10 = {0.f,0.f,0.f,0.f}, acc11 = {0.f,0.f,0.f,0.f};

    float wreg[2][4];
    U128  areg[2][2];

    __syncthreads();                     // previous job's LDS reads done
    ld_B(0, wreg[0]); ld_A(0, areg[0][0], areg[0][1]);
    if (NS > 1) { ld_B(1, wreg[1]); ld_A(1, areg[1][0], areg[1][1]); }

    #pragma unroll
    for (int s = 0; s < NS; ++s) {
        const int pb_ = s & 1;
        uint2 pk;
        pk.x = pk2(wreg[pb_][0], wreg[pb_][1]);
        pk.y = pk2(wreg[pb_][2], wreg[pb_][3]);
        *reinterpret_cast<uint2*>(&bs[pb_][fI][lp][j0]) = pk;
        U128 a0 = areg[pb_][0], a1 = areg[pb_][1];
        if (s + 2 < NS) {                // prefetch 2 ahead into freed slot
            ld_B(s + 2, wreg[pb_]);
            ld_A(s + 2, areg[pb_][0], areg[pb_][1]);
        }
        __syncthreads();                 // bs[pb_] visible (1 barrier/step)
        U128 b0, b1;
        b0.u4 = *reinterpret_cast<const uint4*>(&bs[pb_][0][l][0]);
        b1.u4 = *reinterpret_cast<const uint4*>(&bs[pb_][1][l][0]);
        acc00 = __builtin_amdgcn_mfma_f32_16x16x32_bf16(a0.s8, b0.s8, acc00, 0, 0, 0);
        acc01 = __builtin_amdgcn_mfma_f32_16x16x32_bf16(a0.s8, b1.s8, acc01, 0, 0, 0);
        acc10 = __builtin_amdgcn_mfma_f32_16x16x32_bf16(a1.s8, b0.s8, acc10, 0, 0, 0);
        acc11 = __builtin_amdgcn_mfma_f32_16x16x32_bf16(a1.s8, b1.s8, acc11, 0, 0, 0);
    }

    // C/D: col = l&15, row = (l>>4)*4 + r  (HW-validated)
    float* pb = part + (size_t)sp * B * NP;
    const int colB = n0 + (l & 15);
    const int rsub = (l >> 4) << 2;
    #pragma unroll
    for (int mi = 0; mi < 2; ++mi) {
        const int row = wv * 32 + mi * 16 + rsub;
        const f32x4 c0 = mi ? acc10 : acc00;
        const f32x4 c1 = mi ? acc11 : acc01;
        #pragma unroll
        for (int r = 0; r < 4; ++r) {
            pb[(size_t)(row + r) * NP + colB]      = c0[r];
            pb[(size_t)(row + r) * NP + colB + 16] = c1[r];
        }
    }
}

// finalize mid-layer: reduce split-K + blended bias + ELU, emit next A-frags
// (coef-folded bf16, incl. z cols). Thread owns (b, 4 consecutive k).
template<int S>
__device__ __forceinline__ void fin_mid(
    const float* __restrict__ part, const float* __restrict__ coef,
    const float* __restrict__ bias, const float* __restrict__ z,
    ushort* __restrict__ anext)
{
    for (int idx = blockIdx.x * NT + threadIdx.x; idx < B * (K2 / 4);
         idx += GRID * NT) {
        const int b  = idx / (K2 / 4);
        const int o4 = (idx % (K2 / 4)) * 4;

        float vx, vy, vz2, vw;
        if (o4 < H_DIM) {
            float s0 = 0.f, s1 = 0.f, s2 = 0.f, s3 = 0.f;
            #pragma unroll 4
            for (int s = 0; s < S; ++s) {
                const float4 p = *reinterpret_cast<const float4*>(
                    part + ((size_t)s * B + b) * H_DIM + o4);
                s0 += p.x; s1 += p.y; s2 += p.z; s3 += p.w;
            }
            #pragma unroll
            for (int e = 0; e < E; ++e) {
                const float c = coef[b * E + e];
                const float4 bb = *reinterpret_cast<const float4*>(
                    bias + (size_t)e * H_DIM + o4);
                s0 = fmaf(c, bb.x, s0); s1 = fmaf(c, bb.y, s1);
                s2 = fmaf(c, bb.z, s2); s3 = fmaf(c, bb.w, s3);
            }
            vx  = s0 < 0.f ? expm1f(s0) : s0;
            vy  = s1 < 0.f ? expm1f(s1) : s1;
            vz2 = s2 < 0.f ? expm1f(s2) : s2;
            vw  = s3 < 0.f ? expm1f(s3) : s3;
        } else {
            const float4 zv = *reinterpret_cast<const float4*>(
                z + b * ZD + (o4 - H_DIM));
            vx = zv.x; vy = zv.y; vz2 = zv.z; vw = zv.w;
        }

        const int kb = o4 >> 5;
        const int l  = (((o4 >> 3) & 3) << 4) | (b & 15);
        const int j0 = o4 & 7;
        const int m  = b >> 4;
        #pragma unroll
        for (int e = 0; e < E; ++e) {
            const float c = coef[b * E + e];
            uint2 pk;
            pk.x = pk2(vx * c, vy * c);
            pk.y = pk2(vz2 * c, vw * c);
            *reinterpret_cast<uint2*>(
                anext + ((((size_t)e * KB23 + kb) * 8 + m) * 64 + l) * 8 + j0) = pk;
        }
    }
}

// ---------------------------------------------------------------------------
// The whole network in one persistent kernel. 256 blocks x 256 threads
// (co-resident by construction: 4 waves/block fit any CU at any VGPR count).
// ---------------------------------------------------------------------------
__global__ __launch_bounds__(NT) void moe_net(
    const float* __restrict__ x, const float* __restrict__ coef,
    const float* __restrict__ z,
    const float* __restrict__ w1, const float* __restrict__ b1,
    const float* __restrict__ w2, const float* __restrict__ b2,
    const float* __restrict__ w3, const float* __restrict__ b3,
    ushort* a1, ushort* a2, ushort* a3, float* part,
    int* bars, float* out)
{
    __shared__ ushort bs[2][2][64][8];   // dbuf x frag x lane x j, 4 KB
    const int bid = blockIdx.x;
    const int tid = threadIdx.x;

    // P0: A1 frags [E][KB1][8][64][8]
    for (int u = bid * NT + tid; u < E * KB1 * 8 * 64; u += GRID * NT) {
        const int l = u & 63;
        int t = u >> 6;
        const int m = t & 7; t >>= 3;
        const int kb = t % KB1; const int e = t / KB1;
        const int row = m * 16 + (l & 15);
        const int k0  = kb * 32 + ((l >> 4) << 3);
        const float c = coef[row * E + e];
        const float4 v0 = *reinterpret_cast<const float4*>(x + (size_t)row * IN_DIM + k0);
        const float4 v1 = *reinterpret_cast<const float4*>(x + (size_t)row * IN_DIM + k0 + 4);
        U128 r;
        r.us[0] = f2bf(v0.x * c); r.us[1] = f2bf(v0.y * c);
        r.us[2] = f2bf(v0.z * c); r.us[3] = f2bf(v0.w * c);
        r.us[4] = f2bf(v1.x * c); r.us[5] = f2bf(v1.y * c);
        r.us[6] = f2bf(v1.z * c); r.us[7] = f2bf(v1.w * c);
        *reinterpret_cast<uint4*>(a1 + (size_t)u * 8) = r.u4;
    }
    gbar(bars, 0);

    // P1: L1 gemm — 16 n-tiles x 13 splits (KPB=4), <=1 job/block
    for (int job = bid; job < 16 * S1; job += GRID)
        gemm_job<KB1, 4, H_DIM, H_DIM>((const uint4*)a1, w1, part,
                                       job & 15, job >> 4, bs);
    gbar(bars, 1);

    // P2: fin1 -> a2
    fin_mid<S1>(part, coef, b1, z, a2);
    gbar(bars, 2);

    // P3: L2 gemm — 16 x 17
    for (int job = bid; job < 16 * KB23; job += GRID)
        gemm_job<KB23, 1, H_DIM, H_DIM>((const uint4*)a2, w2, part,
                                        job & 15, job >> 4, bs);
    gbar(bars, 3);

    // P4: fin2 -> a3
    fin_mid<KB23>(part, coef, b2, z, a3);
    gbar(bars, 4);

    // P5: L3 gemm — 20 x 17, cols padded to 640
    for (int job = bid; job < 20 * KB23; job += GRID)
        gemm_job<KB23, 1, OUT_DIM, NPAD3>((const uint4*)a3, w3, part,
                                          job % 20, job / 20, bs);
    gbar(bars, 5);

    // P6: fin3 -> out
    for (int idx = bid * NT + tid; idx < B * OUT_DIM; idx += GRID * NT) {
        const int b = idx / OUT_DIM;
        const int o = idx - b * OUT_DIM;
        float v = 0.f;
        #pragma unroll 4
        for (int s = 0; s < KB23; ++s)
            v += part[((size_t)s * B + b) * NPAD3 + o];
        #pragma unroll
        for (int e = 0; e < E; ++e)
            v = fmaf(coef[b * E + e], b3[(size_t)e * OUT_DIM + o], v);
        out[idx] = v;
    }
}

extern "C" void kernel_launch(void* const* d_in, const int* in_sizes, int n_in,
                              void* d_out, int out_size, void* d_ws, size_t ws_size,
                              hipStream_t stream)
{
    const float* p_prev = (const float*)d_in[0];
    const float* coef   = (const float*)d_in[1];
    const float* z      = (const float*)d_in[2];
    const float* w1     = (const float*)d_in[3];
    const float* b1     = (const float*)d_in[4];
    const float* w2     = (const float*)d_in[5];
    const float* b2     = (const float*)d_in[6];
    const float* w3     = (const float*)d_in[7];
    const float* b3     = (const float*)d_in[8];
    float* out = (float*)d_out;

    // ws layout: bars | a1 | a2 | a3 | part   (~9.8 MB total)
    char* p = (char*)d_ws;
    int* bars = (int*)p;     p += 256;
    ushort* a1 = (ushort*)p; p += (size_t)E * KB1  * 8 * 64 * 16;  // 2,555,904
    ushort* a2 = (ushort*)p; p += (size_t)E * KB23 * 8 * 64 * 16;  //   835,584
    ushort* a3 = (ushort*)p; p += (size_t)E * KB23 * 8 * 64 * 16;  //   835,584
    float* part = (float*)p;  // max(13*B*512, 17*B*640)*4 = 5,570,560

    hipMemsetAsync(bars, 0, 256, stream);   // reset grid-barrier slots
    moe_net<<<GRID, NT, 0, stream>>>(p_prev, coef, z, w1, b1, w2, b2, w3, b3,
                                     a1, a2, a3, part, bars, out);
}

// Round 8
// 122.543 us; speedup vs baseline: 2.0927x; 2.0881x over previous
//
#include <hip/hip_runtime.h>
#include <math.h>

#define B 128
#define E 6
#define IN_DIM 1664
#define H_DIM 512
#define OUT_DIM 618
#define ZD 32
#define K2 544
#define KB1 52            // k32-blocks in L1
#define KB23 17           // k32-blocks in L2/L3
#define NPAD3 640         // L3 padded col space (frags + partials)
#define S1 13             // L1 split-K (KPB=4)
#define S23 9             // L2/L3 split-K (8 splits of 2kb + 1 of 1kb)
#define GRID 256
#define NT 256

typedef __attribute__((ext_vector_type(8))) short short8;
typedef __attribute__((ext_vector_type(4))) float f32x4;
union U128 { uint4 u4; short8 s8; ushort us[8]; };

__device__ __forceinline__ ushort f2bf(float f) {   // fp32 -> bf16 RNE
    uint u = __float_as_uint(f);
    u += 0x7fffu + ((u >> 16) & 1u);
    return (ushort)(u >> 16);
}
__device__ __forceinline__ uint pk2(float a, float b) {
    return (uint)f2bf(a) | ((uint)f2bf(b) << 16);
}

// ---------------------------------------------------------------------------
// Contention-free grid barrier (cross-XCD safe; fencing protocol identical to
// the HW-validated r7 version, topology changed):
//  - arrive[bid]: one 64B line per block, written once per barrier (no RMW,
//    no sharing). release[i]: one line, written once by block 0.
//  - block 0: thread t polls arrive slot of block t; all other blocks spin
//    read-only on release[i].
// Slots zeroed per call by captured hipMemsetAsync.
// ---------------------------------------------------------------------------
__device__ __forceinline__ void gbar(uint* arrive, uint* release, int i) {
    __syncthreads();
    if (blockIdx.x == 0) {
        if (threadIdx.x > 0) {               // threads 1..255 <-> blocks 1..255
            while (__hip_atomic_load(&arrive[threadIdx.x * 16],
                                     __ATOMIC_RELAXED,
                                     __HIP_MEMORY_SCOPE_AGENT) < (uint)(i + 1))
                __builtin_amdgcn_s_sleep(2);
        }
        __syncthreads();
        if (threadIdx.x == 0) {
            __threadfence();                 // wb own writes + inv stale lines
            __hip_atomic_store(&release[i * 16], 1u, __ATOMIC_RELAXED,
                               __HIP_MEMORY_SCOPE_AGENT);
        }
    } else {
        if (threadIdx.x == 0) {
            __threadfence();                 // release this block's phase writes
            __hip_atomic_store(&arrive[blockIdx.x * 16], (uint)(i + 1),
                               __ATOMIC_RELAXED, __HIP_MEMORY_SCOPE_AGENT);
            while (__hip_atomic_load(&release[i * 16], __ATOMIC_RELAXED,
                                     __HIP_MEMORY_SCOPE_AGENT) == 0)
                __builtin_amdgcn_s_sleep(2);
            __threadfence();                 // acquire: invalidate caches
        }
    }
    __syncthreads();
}

// ---------------------------------------------------------------------------
// One gemm job: block tile 128 rows x 32 cols at (nt, kb0..kb0+KPB-1).
// Per step (e,kb): W fp32 32k x 32n tile -> regs -> bf16 -> LDS frag layout
// (double-buffered, 1 barrier/step); A-frags preconverted. 2-deep register
// prefetch. Frag math HW-validated (r3-r7).
// ---------------------------------------------------------------------------
template<int KBTOT, int KPB, int NW, int NP>
__device__ __forceinline__ void gemm_job(
    const uint4* __restrict__ afrag,   // [E][KBTOT][8][64] 16B frags
    const float* __restrict__ w,       // [E][KBTOT*32][NW] fp32
    float* __restrict__ part,          // [S][B][NP]
    int nt, int kb0, int sp, ushort (*bs)[2][64][8])
{
    constexpr int NS = E * KPB;
    const int tid = threadIdx.x;
    const int l  = tid & 63;
    const int wv = tid >> 6;
    const int n0 = nt * 32;
    const int tn  = tid & 31;
    const int tkq = tid >> 5;                        // 0..7
    const int lp  = ((tkq >> 1) << 4) | (tn & 15);   // frag lane
    const int fI  = tn >> 4;                         // frag 0/1
    const int j0  = (tkq & 1) << 2;                  // j offset 0/4
    const int colW = n0 + tn;

    auto ld_B = [&](int s, float* r) {
        const int e = s % E, kb = kb0 + s / E;
        const float* src = w + ((size_t)e * (KBTOT * 32) + kb * 32 + tkq * 4) * NW + colW;
        #pragma unroll
        for (int j = 0; j < 4; ++j)
            r[j] = (NW == NP || colW < NW) ? src[(size_t)j * NW] : 0.f;
    };
    auto ld_A = [&](int s, U128& x0, U128& x1) {
        const int e = s % E, kb = kb0 + s / E;
        const size_t ab = ((size_t)e * KBTOT + kb) * 8;
        x0.u4 = afrag[(ab + 2 * wv) * 64 + l];
        x1.u4 = afrag[(ab + 2 * wv + 1) * 64 + l];
    };

    f32x4 acc00 = {0.f,0.f,0.f,0.f}, acc01 = {0.f,0.f,0.f,0.f};
    f32x4 acc10 = {0.f,0.f,0.f,0.f}, acc11 = {0.f,0.f,0.f,0.f};

    float wreg[2][4];
    U128  areg[2][2];

    __syncthreads();                     // previous job's LDS reads done
    ld_B(0, wreg[0]); ld_A(0, areg[0][0], areg[0][1]);
    if (NS > 1) { ld_B(1, wreg[1]); ld_A(1, areg[1][0], areg[1][1]); }

    #pragma unroll
    for (int s = 0; s < NS; ++s) {
        const int pb_ = s & 1;
        uint2 pk;
        pk.x = pk2(wreg[pb_][0], wreg[pb_][1]);
        pk.y = pk2(wreg[pb_][2], wreg[pb_][3]);
        *reinterpret_cast<uint2*>(&bs[pb_][fI][lp][j0]) = pk;
        U128 a0 = areg[pb_][0], a1 = areg[pb_][1];
        if (s + 2 < NS) {                // prefetch 2 ahead into freed slot
            ld_B(s + 2, wreg[pb_]);
            ld_A(s + 2, areg[pb_][0], areg[pb_][1]);
        }
        __syncthreads();                 // bs[pb_] visible (1 barrier/step)
        U128 b0, b1;
        b0.u4 = *reinterpret_cast<const uint4*>(&bs[pb_][0][l][0]);
        b1.u4 = *reinterpret_cast<const uint4*>(&bs[pb_][1][l][0]);
        acc00 = __builtin_amdgcn_mfma_f32_16x16x32_bf16(a0.s8, b0.s8, acc00, 0, 0, 0);
        acc01 = __builtin_amdgcn_mfma_f32_16x16x32_bf16(a0.s8, b1.s8, acc01, 0, 0, 0);
        acc10 = __builtin_amdgcn_mfma_f32_16x16x32_bf16(a1.s8, b0.s8, acc10, 0, 0, 0);
        acc11 = __builtin_amdgcn_mfma_f32_16x16x32_bf16(a1.s8, b1.s8, acc11, 0, 0, 0);
    }

    // C/D: col = l&15, row = (l>>4)*4 + r  (HW-validated)
    float* pb = part + (size_t)sp * B * NP;
    const int colB = n0 + (l & 15);
    const int rsub = (l >> 4) << 2;
    #pragma unroll
    for (int mi = 0; mi < 2; ++mi) {
        const int row = wv * 32 + mi * 16 + rsub;
        const f32x4 c0 = mi ? acc10 : acc00;
        const f32x4 c1 = mi ? acc11 : acc01;
        #pragma unroll
        for (int r = 0; r < 4; ++r) {
            pb[(size_t)(row + r) * NP + colB]      = c0[r];
            pb[(size_t)(row + r) * NP + colB + 16] = c1[r];
        }
    }
}

// finalize mid-layer: reduce split-K + blended bias + ELU, emit next A-frags.
template<int S>
__device__ __forceinline__ void fin_mid(
    const float* __restrict__ part, const float* __restrict__ coef,
    const float* __restrict__ bias, const float* __restrict__ z,
    ushort* __restrict__ anext)
{
    for (int idx = blockIdx.x * NT + threadIdx.x; idx < B * (K2 / 4);
         idx += GRID * NT) {
        const int b  = idx / (K2 / 4);
        const int o4 = (idx % (K2 / 4)) * 4;

        float vx, vy, vz2, vw;
        if (o4 < H_DIM) {
            float s0 = 0.f, s1 = 0.f, s2 = 0.f, s3 = 0.f;
            #pragma unroll
            for (int s = 0; s < S; ++s) {
                const float4 p = *reinterpret_cast<const float4*>(
                    part + ((size_t)s * B + b) * H_DIM + o4);
                s0 += p.x; s1 += p.y; s2 += p.z; s3 += p.w;
            }
            #pragma unroll
            for (int e = 0; e < E; ++e) {
                const float c = coef[b * E + e];
                const float4 bb = *reinterpret_cast<const float4*>(
                    bias + (size_t)e * H_DIM + o4);
                s0 = fmaf(c, bb.x, s0); s1 = fmaf(c, bb.y, s1);
                s2 = fmaf(c, bb.z, s2); s3 = fmaf(c, bb.w, s3);
            }
            vx  = s0 < 0.f ? expm1f(s0) : s0;
            vy  = s1 < 0.f ? expm1f(s1) : s1;
            vz2 = s2 < 0.f ? expm1f(s2) : s2;
            vw  = s3 < 0.f ? expm1f(s3) : s3;
        } else {
            const float4 zv = *reinterpret_cast<const float4*>(
                z + b * ZD + (o4 - H_DIM));
            vx = zv.x; vy = zv.y; vz2 = zv.z; vw = zv.w;
        }

        const int kb = o4 >> 5;
        const int l  = (((o4 >> 3) & 3) << 4) | (b & 15);
        const int j0 = o4 & 7;
        const int m  = b >> 4;
        #pragma unroll
        for (int e = 0; e < E; ++e) {
            const float c = coef[b * E + e];
            uint2 pk;
            pk.x = pk2(vx * c, vy * c);
            pk.y = pk2(vz2 * c, vw * c);
            *reinterpret_cast<uint2*>(
                anext + ((((size_t)e * KB23 + kb) * 8 + m) * 64 + l) * 8 + j0) = pk;
        }
    }
}

// ---------------------------------------------------------------------------
// Whole network, one persistent kernel: 256 blocks x 256 threads.
// ---------------------------------------------------------------------------
__global__ __launch_bounds__(NT) void moe_net(
    const float* __restrict__ x, const float* __restrict__ coef,
    const float* __restrict__ z,
    const float* __restrict__ w1, const float* __restrict__ b1,
    const float* __restrict__ w2, const float* __restrict__ b2,
    const float* __restrict__ w3, const float* __restrict__ b3,
    ushort* a1, ushort* a2, ushort* a3, float* part,
    uint* arrive, uint* release, float* out)
{
    __shared__ ushort bs[2][2][64][8];   // dbuf x frag x lane x j, 4 KB
    const int bid = blockIdx.x;
    const int tid = threadIdx.x;

    // P0: A1 frags [E][KB1][8][64][8]
    for (int u = bid * NT + tid; u < E * KB1 * 8 * 64; u += GRID * NT) {
        const int l = u & 63;
        int t = u >> 6;
        const int m = t & 7; t >>= 3;
        const int kb = t % KB1; const int e = t / KB1;
        const int row = m * 16 + (l & 15);
        const int k0  = kb * 32 + ((l >> 4) << 3);
        const float c = coef[row * E + e];
        const float4 v0 = *reinterpret_cast<const float4*>(x + (size_t)row * IN_DIM + k0);
        const float4 v1 = *reinterpret_cast<const float4*>(x + (size_t)row * IN_DIM + k0 + 4);
        U128 r;
        r.us[0] = f2bf(v0.x * c); r.us[1] = f2bf(v0.y * c);
        r.us[2] = f2bf(v0.z * c); r.us[3] = f2bf(v0.w * c);
        r.us[4] = f2bf(v1.x * c); r.us[5] = f2bf(v1.y * c);
        r.us[6] = f2bf(v1.z * c); r.us[7] = f2bf(v1.w * c);
        *reinterpret_cast<uint4*>(a1 + (size_t)u * 8) = r.u4;
    }
    gbar(arrive, release, 0);

    // P1: L1 gemm — 16 n-tiles x 13 splits (KPB=4) = 208 jobs (<=1/block)
    for (int job = bid; job < 16 * S1; job += GRID)
        gemm_job<KB1, 4, H_DIM, H_DIM>((const uint4*)a1, w1, part,
                                       job & 15, (job >> 4) * 4, job >> 4, bs);
    gbar(arrive, release, 1);

    // P2: fin1 -> a2
    fin_mid<S1>(part, coef, b1, z, a2);
    gbar(arrive, release, 2);

    // P3: L2 gemm — 16 n-tiles x 9 splits (8x2kb + 1x1kb) = 144 jobs
    for (int job = bid; job < 16 * S23; job += GRID) {
        const int nt = job & 15, sp = job >> 4;
        if (sp < 8)
            gemm_job<KB23, 2, H_DIM, H_DIM>((const uint4*)a2, w2, part,
                                            nt, sp * 2, sp, bs);
        else
            gemm_job<KB23, 1, H_DIM, H_DIM>((const uint4*)a2, w2, part,
                                            nt, 16, sp, bs);
    }
    gbar(arrive, release, 3);

    // P4: fin2 -> a3
    fin_mid<S23>(part, coef, b2, z, a3);
    gbar(arrive, release, 4);

    // P5: L3 gemm — 20 n-tiles x 9 splits = 180 jobs, cols padded to 640
    for (int job = bid; job < 20 * S23; job += GRID) {
        const int nt = job % 20, sp = job / 20;
        if (sp < 8)
            gemm_job<KB23, 2, OUT_DIM, NPAD3>((const uint4*)a3, w3, part,
                                              nt, sp * 2, sp, bs);
        else
            gemm_job<KB23, 1, OUT_DIM, NPAD3>((const uint4*)a3, w3, part,
                                              nt, 16, sp, bs);
    }
    gbar(arrive, release, 5);

    // P6: fin3 -> out
    for (int idx = bid * NT + tid; idx < B * OUT_DIM; idx += GRID * NT) {
        const int b = idx / OUT_DIM;
        const int o = idx - b * OUT_DIM;
        float v = 0.f;
        #pragma unroll 3
        for (int s = 0; s < S23; ++s)
            v += part[((size_t)s * B + b) * NPAD3 + o];
        #pragma unroll
        for (int e = 0; e < E; ++e)
            v = fmaf(coef[b * E + e], b3[(size_t)e * OUT_DIM + o], v);
        out[idx] = v;
    }
}

extern "C" void kernel_launch(void* const* d_in, const int* in_sizes, int n_in,
                              void* d_out, int out_size, void* d_ws, size_t ws_size,
                              hipStream_t stream)
{
    const float* p_prev = (const float*)d_in[0];
    const float* coef   = (const float*)d_in[1];
    const float* z      = (const float*)d_in[2];
    const float* w1     = (const float*)d_in[3];
    const float* b1     = (const float*)d_in[4];
    const float* w2     = (const float*)d_in[5];
    const float* b2     = (const float*)d_in[6];
    const float* w3     = (const float*)d_in[7];
    const float* b3     = (const float*)d_in[8];
    float* out = (float*)d_out;

    // ws layout: arrive(16KB) | release(2KB) | a1 | a2 | a3 | part
    char* p = (char*)d_ws;
    uint* arrive  = (uint*)p; p += GRID * 64;                      // 16,384
    uint* release = (uint*)p; p += 32 * 64;                        //  2,048
    ushort* a1 = (ushort*)p;  p += (size_t)E * KB1  * 8 * 64 * 16; // 2,555,904
    ushort* a2 = (ushort*)p;  p += (size_t)E * KB23 * 8 * 64 * 16; //   835,584
    ushort* a3 = (ushort*)p;  p += (size_t)E * KB23 * 8 * 64 * 16; //   835,584
    float* part = (float*)p;  // max(13*B*512, 9*B*640)*4 = 3,407,872

    hipMemsetAsync(arrive, 0, GRID * 64 + 32 * 64, stream);  // reset barrier slots
    moe_net<<<GRID, NT, 0, stream>>>(p_prev, coef, z, w1, b1, w2, b2, w3, b3,
                                     a1, a2, a3, part, arrive, release, out);
}

// Round 9
// 81.254 us; speedup vs baseline: 3.1562x; 1.5082x over previous
//
#include <hip/hip_runtime.h>
#include <hip/hip_bf16.h>
#include <math.h>

#define B 128
#define E 6
#define IN_DIM 1664
#define H_DIM 512
#define OUT_DIM 618
#define ZD 32
#define K2 544
#define KB1 52            // k32-blocks in L1
#define NPAD3 640         // L3 padded col space (partials)
#define S1 13             // L1 split-K (KPB=4)
#define S23 9             // L2/L3 split-K (8x2kb + 1x1kb z-split)

typedef __attribute__((ext_vector_type(8))) short short8;
typedef __attribute__((ext_vector_type(4))) float f32x4;
union U128 { uint4 u4; short8 s8; ushort us[8]; };

__device__ __forceinline__ ushort f2bf(float f) {   // fp32 -> bf16 RNE
    uint u = __float_as_uint(f);
    u += 0x7fffu + ((u >> 16) & 1u);
    return (ushort)(u >> 16);
}
__device__ __forceinline__ uint pk2(float a, float b) {
    return (uint)f2bf(a) | ((uint)f2bf(b) << 16);
}
__device__ __forceinline__ float elu1(float x) { return x < 0.f ? expm1f(x) : x; }

// Shared MFMA core pieces (HW-validated r3-r8):
//  A frag (e,kb,m): lane l -> row 16m+(l&15), k = 32kb+(l>>4)*8+j
//  B frag (e,kb,nf): lane l -> col 16nf+(l&15), k = 32kb+(l>>4)*8+j
//  C/D: col = l&15, row = (l>>4)*4 + r

// ---------------------------------------------------------------------------
// gemm1: L1. Block tile 128 rows x 32 cols, KPB=4 (24 steps). A-frags built
// in-register from fp32 x * coef (1-kb-deep x prefetch); W fp32 -> bf16 ->
// LDS frags (dbuf, 2-step-deep reg prefetch, 1 barrier/step).
// ---------------------------------------------------------------------------
__global__ __launch_bounds__(256) void gemm1(
    const float* __restrict__ x,     // [B][IN_DIM]
    const float* __restrict__ coef,  // [B][E]
    const float* __restrict__ w,     // [E][IN_DIM][H_DIM]
    float* __restrict__ part)        // [S1][B][H_DIM]
{
    const int tid = threadIdx.x;
    const int l = tid & 63, wv = tid >> 6;
    const int n0 = blockIdx.x * 32, kb0 = blockIdx.y * 4;
    const int tn = tid & 31, tkq = tid >> 5;
    const int lp = ((tkq >> 1) << 4) | (tn & 15);
    const int fI = tn >> 4, j0 = (tkq & 1) << 2;
    const int colW = n0 + tn;
    const int row0 = 32 * wv + (l & 15), row1 = row0 + 16, kq = l >> 4;

    __shared__ ushort bs[2][2][64][8];

    float ce0[E], ce1[E];
    #pragma unroll
    for (int e = 0; e < E; ++e) {
        ce0[e] = coef[row0 * E + e];
        ce1[e] = coef[row1 * E + e];
    }

    auto ld_B = [&](int s, float* r) {
        const int e = s % E, kb = kb0 + s / E;
        const float* src = w + ((size_t)e * IN_DIM + kb * 32 + tkq * 4) * H_DIM + colW;
        #pragma unroll
        for (int j = 0; j < 4; ++j) r[j] = src[(size_t)j * H_DIM];
    };
    auto ld_X = [&](int kb, float4* xr) {
        const float* p0 = x + (size_t)row0 * IN_DIM + kb * 32 + kq * 8;
        const float* p1 = x + (size_t)row1 * IN_DIM + kb * 32 + kq * 8;
        xr[0] = *reinterpret_cast<const float4*>(p0);
        xr[1] = *reinterpret_cast<const float4*>(p0 + 4);
        xr[2] = *reinterpret_cast<const float4*>(p1);
        xr[3] = *reinterpret_cast<const float4*>(p1 + 4);
    };

    f32x4 acc00 = {0.f,0.f,0.f,0.f}, acc01 = {0.f,0.f,0.f,0.f};
    f32x4 acc10 = {0.f,0.f,0.f,0.f}, acc11 = {0.f,0.f,0.f,0.f};

    float wreg[2][4];
    float4 xreg[2][4];
    ld_B(0, wreg[0]); ld_B(1, wreg[1]);
    ld_X(kb0, xreg[0]); ld_X(kb0 + 1, xreg[1]);

    #pragma unroll
    for (int s = 0; s < E * 4; ++s) {
        const int pb_ = s & 1, e = s % E, kbi = s / E;
        uint2 pk;
        pk.x = pk2(wreg[pb_][0], wreg[pb_][1]);
        pk.y = pk2(wreg[pb_][2], wreg[pb_][3]);
        *reinterpret_cast<uint2*>(&bs[pb_][fI][lp][j0]) = pk;

        // A frags from x regs (x independent of e -> reused 6 steps)
        const float4* xc = xreg[kbi & 1];
        U128 a0, a1;
        a0.us[0] = f2bf(xc[0].x * ce0[e]); a0.us[1] = f2bf(xc[0].y * ce0[e]);
        a0.us[2] = f2bf(xc[0].z * ce0[e]); a0.us[3] = f2bf(xc[0].w * ce0[e]);
        a0.us[4] = f2bf(xc[1].x * ce0[e]); a0.us[5] = f2bf(xc[1].y * ce0[e]);
        a0.us[6] = f2bf(xc[1].z * ce0[e]); a0.us[7] = f2bf(xc[1].w * ce0[e]);
        a1.us[0] = f2bf(xc[2].x * ce1[e]); a1.us[1] = f2bf(xc[2].y * ce1[e]);
        a1.us[2] = f2bf(xc[2].z * ce1[e]); a1.us[3] = f2bf(xc[2].w * ce1[e]);
        a1.us[4] = f2bf(xc[3].x * ce1[e]); a1.us[5] = f2bf(xc[3].y * ce1[e]);
        a1.us[6] = f2bf(xc[3].z * ce1[e]); a1.us[7] = f2bf(xc[3].w * ce1[e]);

        if (s + 2 < E * 4) ld_B(s + 2, wreg[pb_]);          // W prefetch
        if (e == E - 1 && kbi + 2 < 4)                      // x prefetch
            ld_X(kb0 + kbi + 2, xreg[kbi & 1]);

        __syncthreads();
        U128 b0, b1;
        b0.u4 = *reinterpret_cast<const uint4*>(&bs[pb_][0][l][0]);
        b1.u4 = *reinterpret_cast<const uint4*>(&bs[pb_][1][l][0]);
        acc00 = __builtin_amdgcn_mfma_f32_16x16x32_bf16(a0.s8, b0.s8, acc00, 0, 0, 0);
        acc01 = __builtin_amdgcn_mfma_f32_16x16x32_bf16(a0.s8, b1.s8, acc01, 0, 0, 0);
        acc10 = __builtin_amdgcn_mfma_f32_16x16x32_bf16(a1.s8, b0.s8, acc10, 0, 0, 0);
        acc11 = __builtin_amdgcn_mfma_f32_16x16x32_bf16(a1.s8, b1.s8, acc11, 0, 0, 0);
    }

    float* pb = part + (size_t)blockIdx.y * B * H_DIM;
    const int colB = n0 + (l & 15);
    const int rsub = (l >> 4) << 2;
    #pragma unroll
    for (int mi = 0; mi < 2; ++mi) {
        const int row = wv * 32 + mi * 16 + rsub;
        const f32x4 c0 = mi ? acc10 : acc00;
        const f32x4 c1 = mi ? acc11 : acc01;
        #pragma unroll
        for (int r = 0; r < 4; ++r) {
            pb[(size_t)(row + r) * H_DIM + colB]      = c0[r];
            pb[(size_t)(row + r) * H_DIM + colB + 16] = c1[r];
        }
    }
}

// ---------------------------------------------------------------------------
// gemm_mid: L2/L3. Prologue: recompute previous layer's finalize for this
// block's own k-range (reduce SPREV splits + blended bias + ELU -> v regs;
// z-split reads z directly). Then the same MFMA pipeline, A-frags from v.
// ---------------------------------------------------------------------------
template<int SPREV, int NW, int NP, int KPB, bool ZS>
__device__ __forceinline__ void gemm_mid_body(
    const float* __restrict__ pin,   // [SPREV][B][512]
    const float* __restrict__ coef,  // [B][E]
    const float* __restrict__ bias,  // [E][512] (prev layer bias)
    const float* __restrict__ z,     // [B][ZD]
    const float* __restrict__ w,     // [E][K2][NW]
    float* __restrict__ pout,        // [S23][B][NP]
    int nt, int kb0, int sp, ushort (*bs)[2][64][8])
{
    constexpr int NS = E * KPB;
    const int tid = threadIdx.x;
    const int l = tid & 63, wv = tid >> 6;
    const int n0 = nt * 32;
    const int tn = tid & 31, tkq = tid >> 5;
    const int lp = ((tkq >> 1) << 4) | (tn & 15);
    const int fI = tn >> 4, j0 = (tkq & 1) << 2;
    const int colW = n0 + tn;
    const int row0 = 32 * wv + (l & 15), row1 = row0 + 16, kq = l >> 4;

    float ce0[E], ce1[E];
    #pragma unroll
    for (int e = 0; e < E; ++e) {
        ce0[e] = coef[row0 * E + e];
        ce1[e] = coef[row1 * E + e];
    }

    // ---- prologue: v = prev-layer activation for this k-range ----
    float v0[KPB * 8], v1[KPB * 8];
    if (ZS) {
        const float4 za = *reinterpret_cast<const float4*>(z + row0 * ZD + kq * 8);
        const float4 zb = *reinterpret_cast<const float4*>(z + row0 * ZD + kq * 8 + 4);
        const float4 zc = *reinterpret_cast<const float4*>(z + row1 * ZD + kq * 8);
        const float4 zd = *reinterpret_cast<const float4*>(z + row1 * ZD + kq * 8 + 4);
        v0[0]=za.x; v0[1]=za.y; v0[2]=za.z; v0[3]=za.w;
        v0[4]=zb.x; v0[5]=zb.y; v0[6]=zb.z; v0[7]=zb.w;
        v1[0]=zc.x; v1[1]=zc.y; v1[2]=zc.z; v1[3]=zc.w;
        v1[4]=zd.x; v1[5]=zd.y; v1[6]=zd.z; v1[7]=zd.w;
    } else {
        #pragma unroll
        for (int kbi = 0; kbi < KPB; ++kbi) {
            const int kk = (kb0 + kbi) * 32 + kq * 8;
            float s0[8] = {0,0,0,0,0,0,0,0}, s1[8] = {0,0,0,0,0,0,0,0};
            #pragma unroll
            for (int s = 0; s < SPREV; ++s) {
                const float* p0 = pin + ((size_t)s * B + row0) * 512 + kk;
                const float* p1 = pin + ((size_t)s * B + row1) * 512 + kk;
                const float4 a = *reinterpret_cast<const float4*>(p0);
                const float4 b = *reinterpret_cast<const float4*>(p0 + 4);
                const float4 c = *reinterpret_cast<const float4*>(p1);
                const float4 d = *reinterpret_cast<const float4*>(p1 + 4);
                s0[0]+=a.x; s0[1]+=a.y; s0[2]+=a.z; s0[3]+=a.w;
                s0[4]+=b.x; s0[5]+=b.y; s0[6]+=b.z; s0[7]+=b.w;
                s1[0]+=c.x; s1[1]+=c.y; s1[2]+=c.z; s1[3]+=c.w;
                s1[4]+=d.x; s1[5]+=d.y; s1[6]+=d.z; s1[7]+=d.w;
            }
            #pragma unroll
            for (int e = 0; e < E; ++e) {
                const float* bp = bias + (size_t)e * 512 + kk;
                const float4 a = *reinterpret_cast<const float4*>(bp);
                const float4 b = *reinterpret_cast<const float4*>(bp + 4);
                s0[0]=fmaf(ce0[e],a.x,s0[0]); s0[1]=fmaf(ce0[e],a.y,s0[1]);
                s0[2]=fmaf(ce0[e],a.z,s0[2]); s0[3]=fmaf(ce0[e],a.w,s0[3]);
                s0[4]=fmaf(ce0[e],b.x,s0[4]); s0[5]=fmaf(ce0[e],b.y,s0[5]);
                s0[6]=fmaf(ce0[e],b.z,s0[6]); s0[7]=fmaf(ce0[e],b.w,s0[7]);
                s1[0]=fmaf(ce1[e],a.x,s1[0]); s1[1]=fmaf(ce1[e],a.y,s1[1]);
                s1[2]=fmaf(ce1[e],a.z,s1[2]); s1[3]=fmaf(ce1[e],a.w,s1[3]);
                s1[4]=fmaf(ce1[e],b.x,s1[4]); s1[5]=fmaf(ce1[e],b.y,s1[5]);
                s1[6]=fmaf(ce1[e],b.z,s1[6]); s1[7]=fmaf(ce1[e],b.w,s1[7]);
            }
            #pragma unroll
            for (int j = 0; j < 8; ++j) {
                v0[kbi * 8 + j] = elu1(s0[j]);
                v1[kbi * 8 + j] = elu1(s1[j]);
            }
        }
    }

    // ---- MFMA pipeline ----
    auto ld_B = [&](int s, float* r) {
        const int e = s % E, kb = kb0 + s / E;
        const float* src = w + ((size_t)e * K2 + kb * 32 + tkq * 4) * NW + colW;
        #pragma unroll
        for (int j = 0; j < 4; ++j)
            r[j] = (NW == NP || colW < NW) ? src[(size_t)j * NW] : 0.f;
    };

    f32x4 acc00 = {0.f,0.f,0.f,0.f}, acc01 = {0.f,0.f,0.f,0.f};
    f32x4 acc10 = {0.f,0.f,0.f,0.f}, acc11 = {0.f,0.f,0.f,0.f};

    float wreg[2][4];
    ld_B(0, wreg[0]);
    if (NS > 1) ld_B(1, wreg[1]);

    #pragma unroll
    for (int s = 0; s < NS; ++s) {
        const int pb_ = s & 1, e = s % E, kbi = s / E;
        uint2 pk;
        pk.x = pk2(wreg[pb_][0], wreg[pb_][1]);
        pk.y = pk2(wreg[pb_][2], wreg[pb_][3]);
        *reinterpret_cast<uint2*>(&bs[pb_][fI][lp][j0]) = pk;

        U128 a0, a1;
        #pragma unroll
        for (int j = 0; j < 8; ++j) {
            a0.us[j] = f2bf(v0[kbi * 8 + j] * ce0[e]);
            a1.us[j] = f2bf(v1[kbi * 8 + j] * ce1[e]);
        }

        if (s + 2 < NS) ld_B(s + 2, wreg[pb_]);

        __syncthreads();
        U128 b0, b1;
        b0.u4 = *reinterpret_cast<const uint4*>(&bs[pb_][0][l][0]);
        b1.u4 = *reinterpret_cast<const uint4*>(&bs[pb_][1][l][0]);
        acc00 = __builtin_amdgcn_mfma_f32_16x16x32_bf16(a0.s8, b0.s8, acc00, 0, 0, 0);
        acc01 = __builtin_amdgcn_mfma_f32_16x16x32_bf16(a0.s8, b1.s8, acc01, 0, 0, 0);
        acc10 = __builtin_amdgcn_mfma_f32_16x16x32_bf16(a1.s8, b0.s8, acc10, 0, 0, 0);
        acc11 = __builtin_amdgcn_mfma_f32_16x16x32_bf16(a1.s8, b1.s8, acc11, 0, 0, 0);
    }

    float* pb = pout + (size_t)sp * B * NP;
    const int colB = n0 + (l & 15);
    const int rsub = (l >> 4) << 2;
    #pragma unroll
    for (int mi = 0; mi < 2; ++mi) {
        const int row = wv * 32 + mi * 16 + rsub;
        const f32x4 c0 = mi ? acc10 : acc00;
        const f32x4 c1 = mi ? acc11 : acc01;
        #pragma unroll
        for (int r = 0; r < 4; ++r) {
            pb[(size_t)(row + r) * NP + colB]      = c0[r];
            pb[(size_t)(row + r) * NP + colB + 16] = c1[r];
        }
    }
}

__global__ __launch_bounds__(256) void gemm_l2(
    const float* __restrict__ part1, const float* __restrict__ coef,
    const float* __restrict__ b1, const float* __restrict__ z,
    const float* __restrict__ w2, float* __restrict__ part2)
{
    __shared__ ushort bs[2][2][64][8];
    const int nt = blockIdx.x, sp = blockIdx.y;
    if (sp < 8)
        gemm_mid_body<S1, H_DIM, H_DIM, 2, false>(part1, coef, b1, z, w2,
                                                  part2, nt, sp * 2, sp, bs);
    else
        gemm_mid_body<S1, H_DIM, H_DIM, 1, true>(part1, coef, b1, z, w2,
                                                 part2, nt, 16, sp, bs);
}

__global__ __launch_bounds__(256) void gemm_l3(
    const float* __restrict__ part2, const float* __restrict__ coef,
    const float* __restrict__ b2, const float* __restrict__ z,
    const float* __restrict__ w3, float* __restrict__ part3)
{
    __shared__ ushort bs[2][2][64][8];
    const int nt = blockIdx.x, sp = blockIdx.y;
    if (sp < 8)
        gemm_mid_body<S23, OUT_DIM, NPAD3, 2, false>(part2, coef, b2, z, w3,
                                                     part3, nt, sp * 2, sp, bs);
    else
        gemm_mid_body<S23, OUT_DIM, NPAD3, 1, true>(part2, coef, b2, z, w3,
                                                    part3, nt, 16, sp, bs);
}

// fin_last: reduce L3 partials (padded stride) + blended bias -> out.
__global__ __launch_bounds__(256) void fin_last(
    const float* __restrict__ part3, const float* __restrict__ coef,
    const float* __restrict__ b3, float* __restrict__ out)
{
    const int idx = blockIdx.x * 256 + threadIdx.x;
    if (idx >= B * OUT_DIM) return;
    const int b = idx / OUT_DIM;
    const int o = idx - b * OUT_DIM;
    float v = 0.f;
    #pragma unroll
    for (int s = 0; s < S23; ++s)
        v += part3[((size_t)s * B + b) * NPAD3 + o];
    #pragma unroll
    for (int e = 0; e < E; ++e)
        v = fmaf(coef[b * E + e], b3[(size_t)e * OUT_DIM + o], v);
    out[idx] = v;
}

extern "C" void kernel_launch(void* const* d_in, const int* in_sizes, int n_in,
                              void* d_out, int out_size, void* d_ws, size_t ws_size,
                              hipStream_t stream)
{
    const float* p_prev = (const float*)d_in[0];
    const float* coef   = (const float*)d_in[1];
    const float* z      = (const float*)d_in[2];
    const float* w1     = (const float*)d_in[3];
    const float* b1     = (const float*)d_in[4];
    const float* w2     = (const float*)d_in[5];
    const float* b2     = (const float*)d_in[6];
    const float* w3     = (const float*)d_in[7];
    const float* b3     = (const float*)d_in[8];
    float* out = (float*)d_out;

    // ws: part1 | part2 | part3  (~8.7 MB, no init required)
    char* p = (char*)d_ws;
    float* part1 = (float*)p; p += (size_t)S1  * B * H_DIM * 4;  // 3,407,872
    float* part2 = (float*)p; p += (size_t)S23 * B * H_DIM * 4;  // 2,359,296
    float* part3 = (float*)p;                                    // 2,949,120

    gemm1<<<dim3(16, S1), 256, 0, stream>>>(p_prev, coef, w1, part1);
    gemm_l2<<<dim3(16, S23), 256, 0, stream>>>(part1, coef, b1, z, w2, part2);
    gemm_l3<<<dim3(20, S23), 256, 0, stream>>>(part2, coef, b2, z, w3, part3);
    fin_last<<<(B * OUT_DIM + 255) / 256, 256, 0, stream>>>(part3, coef, b3, out);
}

// Round 10
// 49.054 us; speedup vs baseline: 5.2279x; 1.6564x over previous
//
#include <hip/hip_runtime.h>
#include <math.h>

#define B 128
#define E 6
#define IN_DIM 1664
#define H_DIM 512
#define OUT_DIM 618
#define ZD 32
#define K2 544
#define S1 13             // L1 split-K (KPB=4)
#define S23 9             // L2/L3 split-K (8x2kb + 1x1kb z-split)

typedef __attribute__((ext_vector_type(8))) short short8;
typedef __attribute__((ext_vector_type(4))) float f32x4;
union U128 { uint4 u4; short8 s8; ushort us[8]; };

__device__ __forceinline__ ushort f2bf(float f) {   // fp32 -> bf16 RNE
    uint u = __float_as_uint(f);
    u += 0x7fffu + ((u >> 16) & 1u);
    return (ushort)(u >> 16);
}
__device__ __forceinline__ uint pk2(float a, float b) {
    return (uint)f2bf(a) | ((uint)f2bf(b) << 16);
}
__device__ __forceinline__ float elu1(float x) { return x < 0.f ? expm1f(x) : x; }

// MFMA frag math (HW-validated r3-r9):
//  A frag (kb,m): lane l -> row 16m+(l&15), k = 32kb+(l>>4)*8+j
//  B frag (kb,nf): lane l -> col 16nf+(l&15), k = 32kb+(l>>4)*8+j
//  C/D: col = l&15, row = (l>>4)*4 + r

// ---------------------------------------------------------------------------
// init_bias: y1,y2,out <- coef-blended biases. Consumers then only need
// elu(y[.]) (mid layers) or nothing (out): bias is pre-added, gemms
// atomically accumulate on top.
// ---------------------------------------------------------------------------
__global__ __launch_bounds__(256) void init_bias(
    const float* __restrict__ coef,
    const float* __restrict__ b1, const float* __restrict__ b2,
    const float* __restrict__ b3,
    float* __restrict__ y1, float* __restrict__ y2, float* __restrict__ out)
{
    const int idx = blockIdx.x * 256 + threadIdx.x;
    if (idx >= B * (2 * H_DIM + OUT_DIM)) return;
    const int b = idx / (2 * H_DIM + OUT_DIM);
    const int o = idx - b * (2 * H_DIM + OUT_DIM);
    float ce[E];
    #pragma unroll
    for (int e = 0; e < E; ++e) ce[e] = coef[b * E + e];
    float v = 0.f;
    if (o < H_DIM) {
        #pragma unroll
        for (int e = 0; e < E; ++e) v = fmaf(ce[e], b1[e * H_DIM + o], v);
        y1[b * H_DIM + o] = v;
    } else if (o < 2 * H_DIM) {
        const int oo = o - H_DIM;
        #pragma unroll
        for (int e = 0; e < E; ++e) v = fmaf(ce[e], b2[e * H_DIM + oo], v);
        y2[b * H_DIM + oo] = v;
    } else {
        const int oo = o - 2 * H_DIM;
        #pragma unroll
        for (int e = 0; e < E; ++e) v = fmaf(ce[e], b3[e * OUT_DIM + oo], v);
        out[b * OUT_DIM + oo] = v;
    }
}

// ---------------------------------------------------------------------------
// gemm1: L1, block tile 128x32, KPB=4 (24 steps). A-frags from fp32 x*coef
// in-register; W fp32 -> bf16 -> LDS frags (dbuf, 2-step prefetch, 1
// barrier/step). Epilogue: atomicAdd into y1 (bias pre-initialized).
// ---------------------------------------------------------------------------
__global__ __launch_bounds__(256) void gemm1(
    const float* __restrict__ x,     // [B][IN_DIM]
    const float* __restrict__ coef,  // [B][E]
    const float* __restrict__ w,     // [E][IN_DIM][H_DIM]
    float* __restrict__ y1)          // [B][H_DIM] accum
{
    const int tid = threadIdx.x;
    const int l = tid & 63, wv = tid >> 6;
    const int n0 = blockIdx.x * 32, kb0 = blockIdx.y * 4;
    const int tn = tid & 31, tkq = tid >> 5;
    const int lp = ((tkq >> 1) << 4) | (tn & 15);
    const int fI = tn >> 4, j0 = (tkq & 1) << 2;
    const int colW = n0 + tn;
    const int row0 = 32 * wv + (l & 15), row1 = row0 + 16, kq = l >> 4;

    __shared__ ushort bs[2][2][64][8];

    float ce0[E], ce1[E];
    #pragma unroll
    for (int e = 0; e < E; ++e) {
        ce0[e] = coef[row0 * E + e];
        ce1[e] = coef[row1 * E + e];
    }

    auto ld_B = [&](int s, float* r) {
        const int e = s % E, kb = kb0 + s / E;
        const float* src = w + ((size_t)e * IN_DIM + kb * 32 + tkq * 4) * H_DIM + colW;
        #pragma unroll
        for (int j = 0; j < 4; ++j) r[j] = src[(size_t)j * H_DIM];
    };
    auto ld_X = [&](int kb, float4* xr) {
        const float* p0 = x + (size_t)row0 * IN_DIM + kb * 32 + kq * 8;
        const float* p1 = x + (size_t)row1 * IN_DIM + kb * 32 + kq * 8;
        xr[0] = *reinterpret_cast<const float4*>(p0);
        xr[1] = *reinterpret_cast<const float4*>(p0 + 4);
        xr[2] = *reinterpret_cast<const float4*>(p1);
        xr[3] = *reinterpret_cast<const float4*>(p1 + 4);
    };

    f32x4 acc00 = {0.f,0.f,0.f,0.f}, acc01 = {0.f,0.f,0.f,0.f};
    f32x4 acc10 = {0.f,0.f,0.f,0.f}, acc11 = {0.f,0.f,0.f,0.f};

    float wreg[2][4];
    float4 xreg[2][4];
    ld_B(0, wreg[0]); ld_B(1, wreg[1]);
    ld_X(kb0, xreg[0]); ld_X(kb0 + 1, xreg[1]);

    #pragma unroll
    for (int s = 0; s < E * 4; ++s) {
        const int pb_ = s & 1, e = s % E, kbi = s / E;
        uint2 pk;
        pk.x = pk2(wreg[pb_][0], wreg[pb_][1]);
        pk.y = pk2(wreg[pb_][2], wreg[pb_][3]);
        *reinterpret_cast<uint2*>(&bs[pb_][fI][lp][j0]) = pk;

        const float4* xc = xreg[kbi & 1];
        U128 a0, a1;
        a0.us[0] = f2bf(xc[0].x * ce0[e]); a0.us[1] = f2bf(xc[0].y * ce0[e]);
        a0.us[2] = f2bf(xc[0].z * ce0[e]); a0.us[3] = f2bf(xc[0].w * ce0[e]);
        a0.us[4] = f2bf(xc[1].x * ce0[e]); a0.us[5] = f2bf(xc[1].y * ce0[e]);
        a0.us[6] = f2bf(xc[1].z * ce0[e]); a0.us[7] = f2bf(xc[1].w * ce0[e]);
        a1.us[0] = f2bf(xc[2].x * ce1[e]); a1.us[1] = f2bf(xc[2].y * ce1[e]);
        a1.us[2] = f2bf(xc[2].z * ce1[e]); a1.us[3] = f2bf(xc[2].w * ce1[e]);
        a1.us[4] = f2bf(xc[3].x * ce1[e]); a1.us[5] = f2bf(xc[3].y * ce1[e]);
        a1.us[6] = f2bf(xc[3].z * ce1[e]); a1.us[7] = f2bf(xc[3].w * ce1[e]);

        if (s + 2 < E * 4) ld_B(s + 2, wreg[pb_]);          // W prefetch
        if (e == E - 1 && kbi + 2 < 4)                      // x prefetch
            ld_X(kb0 + kbi + 2, xreg[kbi & 1]);

        __syncthreads();
        U128 b0, b1;
        b0.u4 = *reinterpret_cast<const uint4*>(&bs[pb_][0][l][0]);
        b1.u4 = *reinterpret_cast<const uint4*>(&bs[pb_][1][l][0]);
        acc00 = __builtin_amdgcn_mfma_f32_16x16x32_bf16(a0.s8, b0.s8, acc00, 0, 0, 0);
        acc01 = __builtin_amdgcn_mfma_f32_16x16x32_bf16(a0.s8, b1.s8, acc01, 0, 0, 0);
        acc10 = __builtin_amdgcn_mfma_f32_16x16x32_bf16(a1.s8, b0.s8, acc10, 0, 0, 0);
        acc11 = __builtin_amdgcn_mfma_f32_16x16x32_bf16(a1.s8, b1.s8, acc11, 0, 0, 0);
    }

    const int colB = n0 + (l & 15);
    const int rsub = (l >> 4) << 2;
    #pragma unroll
    for (int mi = 0; mi < 2; ++mi) {
        const int row = wv * 32 + mi * 16 + rsub;
        const f32x4 c0 = mi ? acc10 : acc00;
        const f32x4 c1 = mi ? acc11 : acc01;
        #pragma unroll
        for (int r = 0; r < 4; ++r) {
            atomicAdd(&y1[(size_t)(row + r) * H_DIM + colB],      c0[r]);
            atomicAdd(&y1[(size_t)(row + r) * H_DIM + colB + 16], c1[r]);
        }
    }
}

// ---------------------------------------------------------------------------
// gemm_mid: L2/L3. Prologue: O(1) loads — yin already holds accum+bias, so
// act = elu(yin) (or raw z for the z-split). Then the same MFMA pipeline;
// epilogue atomicAdds into yout (bias pre-initialized).
// ---------------------------------------------------------------------------
template<int KPB, bool ZS, int NW, bool GUARD>
__device__ __forceinline__ void gemm_mid_body(
    const float* __restrict__ yin,   // [B][H_DIM] accum(+bias) pre-ELU
    const float* __restrict__ coef,  // [B][E]
    const float* __restrict__ z,     // [B][ZD]
    const float* __restrict__ w,     // [E][K2][NW]
    float* __restrict__ yout,        // [B][NW] accum
    int nt, int kb0, ushort (*bs)[2][64][8])
{
    constexpr int NS = E * KPB;
    const int tid = threadIdx.x;
    const int l = tid & 63, wv = tid >> 6;
    const int n0 = nt * 32;
    const int tn = tid & 31, tkq = tid >> 5;
    const int lp = ((tkq >> 1) << 4) | (tn & 15);
    const int fI = tn >> 4, j0 = (tkq & 1) << 2;
    const int colW = n0 + tn;
    const int row0 = 32 * wv + (l & 15), row1 = row0 + 16, kq = l >> 4;

    float ce0[E], ce1[E];
    #pragma unroll
    for (int e = 0; e < E; ++e) {
        ce0[e] = coef[row0 * E + e];
        ce1[e] = coef[row1 * E + e];
    }

    // ---- prologue: per-thread activations for this k-range (8 loads) ----
    float v0[KPB * 8], v1[KPB * 8];
    if (ZS) {
        const float4 za = *reinterpret_cast<const float4*>(z + row0 * ZD + kq * 8);
        const float4 zb = *reinterpret_cast<const float4*>(z + row0 * ZD + kq * 8 + 4);
        const float4 zc = *reinterpret_cast<const float4*>(z + row1 * ZD + kq * 8);
        const float4 zd = *reinterpret_cast<const float4*>(z + row1 * ZD + kq * 8 + 4);
        v0[0]=za.x; v0[1]=za.y; v0[2]=za.z; v0[3]=za.w;
        v0[4]=zb.x; v0[5]=zb.y; v0[6]=zb.z; v0[7]=zb.w;
        v1[0]=zc.x; v1[1]=zc.y; v1[2]=zc.z; v1[3]=zc.w;
        v1[4]=zd.x; v1[5]=zd.y; v1[6]=zd.z; v1[7]=zd.w;
    } else {
        #pragma unroll
        for (int kbi = 0; kbi < KPB; ++kbi) {
            const int kk = (kb0 + kbi) * 32 + kq * 8;
            const float* p0 = yin + (size_t)row0 * H_DIM + kk;
            const float* p1 = yin + (size_t)row1 * H_DIM + kk;
            const float4 a = *reinterpret_cast<const float4*>(p0);
            const float4 b = *reinterpret_cast<const float4*>(p0 + 4);
            const float4 c = *reinterpret_cast<const float4*>(p1);
            const float4 d = *reinterpret_cast<const float4*>(p1 + 4);
            v0[kbi*8+0]=elu1(a.x); v0[kbi*8+1]=elu1(a.y);
            v0[kbi*8+2]=elu1(a.z); v0[kbi*8+3]=elu1(a.w);
            v0[kbi*8+4]=elu1(b.x); v0[kbi*8+5]=elu1(b.y);
            v0[kbi*8+6]=elu1(b.z); v0[kbi*8+7]=elu1(b.w);
            v1[kbi*8+0]=elu1(c.x); v1[kbi*8+1]=elu1(c.y);
            v1[kbi*8+2]=elu1(c.z); v1[kbi*8+3]=elu1(c.w);
            v1[kbi*8+4]=elu1(d.x); v1[kbi*8+5]=elu1(d.y);
            v1[kbi*8+6]=elu1(d.z); v1[kbi*8+7]=elu1(d.w);
        }
    }

    // ---- MFMA pipeline ----
    auto ld_B = [&](int s, float* r) {
        const int e = s % E, kb = kb0 + s / E;
        const float* src = w + ((size_t)e * K2 + kb * 32 + tkq * 4) * NW + colW;
        #pragma unroll
        for (int j = 0; j < 4; ++j)
            r[j] = (!GUARD || colW < NW) ? src[(size_t)j * NW] : 0.f;
    };

    f32x4 acc00 = {0.f,0.f,0.f,0.f}, acc01 = {0.f,0.f,0.f,0.f};
    f32x4 acc10 = {0.f,0.f,0.f,0.f}, acc11 = {0.f,0.f,0.f,0.f};

    float wreg[2][4];
    ld_B(0, wreg[0]);
    if (NS > 1) ld_B(1, wreg[1]);

    #pragma unroll
    for (int s = 0; s < NS; ++s) {
        const int pb_ = s & 1, e = s % E, kbi = s / E;
        uint2 pk;
        pk.x = pk2(wreg[pb_][0], wreg[pb_][1]);
        pk.y = pk2(wreg[pb_][2], wreg[pb_][3]);
        *reinterpret_cast<uint2*>(&bs[pb_][fI][lp][j0]) = pk;

        U128 a0, a1;
        #pragma unroll
        for (int j = 0; j < 8; ++j) {
            a0.us[j] = f2bf(v0[kbi * 8 + j] * ce0[e]);
            a1.us[j] = f2bf(v1[kbi * 8 + j] * ce1[e]);
        }

        if (s + 2 < NS) ld_B(s + 2, wreg[pb_]);

        __syncthreads();
        U128 b0, b1;
        b0.u4 = *reinterpret_cast<const uint4*>(&bs[pb_][0][l][0]);
        b1.u4 = *reinterpret_cast<const uint4*>(&bs[pb_][1][l][0]);
        acc00 = __builtin_amdgcn_mfma_f32_16x16x32_bf16(a0.s8, b0.s8, acc00, 0, 0, 0);
        acc01 = __builtin_amdgcn_mfma_f32_16x16x32_bf16(a0.s8, b1.s8, acc01, 0, 0, 0);
        acc10 = __builtin_amdgcn_mfma_f32_16x16x32_bf16(a1.s8, b0.s8, acc10, 0, 0, 0);
        acc11 = __builtin_amdgcn_mfma_f32_16x16x32_bf16(a1.s8, b1.s8, acc11, 0, 0, 0);
    }

    const int colB = n0 + (l & 15);
    const int rsub = (l >> 4) << 2;
    #pragma unroll
    for (int mi = 0; mi < 2; ++mi) {
        const int row = wv * 32 + mi * 16 + rsub;
        const f32x4 c0 = mi ? acc10 : acc00;
        const f32x4 c1 = mi ? acc11 : acc01;
        #pragma unroll
        for (int r = 0; r < 4; ++r) {
            if (!GUARD || colB < NW)
                atomicAdd(&yout[(size_t)(row + r) * NW + colB], c0[r]);
            if (!GUARD || colB + 16 < NW)
                atomicAdd(&yout[(size_t)(row + r) * NW + colB + 16], c1[r]);
        }
    }
}

__global__ __launch_bounds__(256) void gemm_l2(
    const float* __restrict__ y1, const float* __restrict__ coef,
    const float* __restrict__ z, const float* __restrict__ w2,
    float* __restrict__ y2)
{
    __shared__ ushort bs[2][2][64][8];
    const int nt = blockIdx.x, sp = blockIdx.y;
    if (sp < 8)
        gemm_mid_body<2, false, H_DIM, false>(y1, coef, z, w2, y2, nt, sp * 2, bs);
    else
        gemm_mid_body<1, true, H_DIM, false>(y1, coef, z, w2, y2, nt, 16, bs);
}

__global__ __launch_bounds__(256) void gemm_l3(
    const float* __restrict__ y2, const float* __restrict__ coef,
    const float* __restrict__ z, const float* __restrict__ w3,
    float* __restrict__ out)
{
    __shared__ ushort bs[2][2][64][8];
    const int nt = blockIdx.x, sp = blockIdx.y;
    if (sp < 8)
        gemm_mid_body<2, false, OUT_DIM, true>(y2, coef, z, w3, out, nt, sp * 2, bs);
    else
        gemm_mid_body<1, true, OUT_DIM, true>(y2, coef, z, w3, out, nt, 16, bs);
}

extern "C" void kernel_launch(void* const* d_in, const int* in_sizes, int n_in,
                              void* d_out, int out_size, void* d_ws, size_t ws_size,
                              hipStream_t stream)
{
    const float* p_prev = (const float*)d_in[0];
    const float* coef   = (const float*)d_in[1];
    const float* z      = (const float*)d_in[2];
    const float* w1     = (const float*)d_in[3];
    const float* b1     = (const float*)d_in[4];
    const float* w2     = (const float*)d_in[5];
    const float* b2     = (const float*)d_in[6];
    const float* w3     = (const float*)d_in[7];
    const float* b3     = (const float*)d_in[8];
    float* out = (float*)d_out;

    // ws: y1 | y2  (fp32 accumulators, re-initialized every call)
    float* y1 = (float*)d_ws;            // [B][512] = 256 KB
    float* y2 = y1 + (size_t)B * H_DIM;  // [B][512] = 256 KB

    const int TOT = B * (2 * H_DIM + OUT_DIM);
    init_bias<<<(TOT + 255) / 256, 256, 0, stream>>>(coef, b1, b2, b3, y1, y2, out);
    gemm1<<<dim3(16, S1), 256, 0, stream>>>(p_prev, coef, w1, y1);
    gemm_l2<<<dim3(16, S23), 256, 0, stream>>>(y1, coef, z, w2, y2);
    gemm_l3<<<dim3(20, S23), 256, 0, stream>>>(y2, coef, z, w3, out);
}